// Round 1
// baseline (471.355 us; speedup 1.0000x reference)
//
#include <hip/hip_runtime.h>

#define GAS __attribute__((address_space(1)))
#define LAS __attribute__((address_space(3)))

typedef __attribute__((ext_vector_type(8))) short short8;
typedef __attribute__((ext_vector_type(4))) float f32x4;
typedef unsigned short u16;

// dims
constexpr int cB = 16, cC = 256, cIC = 128, cN = 1024;

__device__ __forceinline__ u16 f2bf(float v) {
    unsigned u = __builtin_bit_cast(unsigned, v);
    return (u16)((u + 0x7fffu + ((u >> 16) & 1u)) >> 16);
}

// ---------------------------------------------------------------------------
// Generic bf16 GEMM, C[m,n] = sum_k A[m,k]*B[n,k]  (both operands K-major)
// 128x128 tile, BK=32, 4 waves (2x2), mfma_f32_16x16x32_bf16, global_load_lds.
// ---------------------------------------------------------------------------
template<bool RELU, bool OBF16, bool RBIAS, bool RESID>
__global__ __launch_bounds__(256) void gemm_bt(
    const u16* __restrict__ A, long long sA, int lda,
    const u16* __restrict__ B, long long sB, int ldb,
    void* __restrict__ C, long long sC, int ldc,
    int K,
    const float* __restrict__ bias,
    const float* __restrict__ resid, long long sR)
{
    __shared__ alignas(16) u16 lsA[128 * 32];
    __shared__ alignas(16) u16 lsB[128 * 32];

    const int tid  = threadIdx.x;
    const int lane = tid & 63;
    const int wave = tid >> 6;
    const int wr = wave >> 1, wc = wave & 1;
    const int bz = blockIdx.z;

    const u16* Ab = A + (long long)bz * sA + (size_t)(blockIdx.x * 128) * lda;
    const u16* Bb = B + (long long)bz * sB + (size_t)(blockIdx.y * 128) * ldb;

    // staging coords: thread t covers 8 contiguous bf16; chunk j adds 64 rows
    const int sr = tid >> 2;          // row 0..63 within chunk
    const int sk = (tid & 3) * 8;     // k offset 0..24

    f32x4 acc[4][4] = {};

    for (int kk = 0; kk < K; kk += 32) {
        const u16* Ak = Ab + kk;
        const u16* Bk = Bb + kk;
        __builtin_amdgcn_global_load_lds((GAS void*)(Ak + (size_t)sr * lda + sk),
                                         (LAS void*)(&lsA[wave << 9]), 16, 0, 0);
        __builtin_amdgcn_global_load_lds((GAS void*)(Ak + (size_t)(sr + 64) * lda + sk),
                                         (LAS void*)(&lsA[2048 + (wave << 9)]), 16, 0, 0);
        __builtin_amdgcn_global_load_lds((GAS void*)(Bk + (size_t)sr * ldb + sk),
                                         (LAS void*)(&lsB[wave << 9]), 16, 0, 0);
        __builtin_amdgcn_global_load_lds((GAS void*)(Bk + (size_t)(sr + 64) * ldb + sk),
                                         (LAS void*)(&lsB[2048 + (wave << 9)]), 16, 0, 0);
        __syncthreads();

        short8 af[4], bfr[4];
        #pragma unroll
        for (int m = 0; m < 4; m++)
            af[m] = *(const short8*)&lsA[(((wr << 6) + (m << 4) + (lane & 15)) << 5) + ((lane >> 4) << 3)];
        #pragma unroll
        for (int n = 0; n < 4; n++)
            bfr[n] = *(const short8*)&lsB[(((wc << 6) + (n << 4) + (lane & 15)) << 5) + ((lane >> 4) << 3)];
        #pragma unroll
        for (int m = 0; m < 4; m++)
            #pragma unroll
            for (int n = 0; n < 4; n++)
                acc[m][n] = __builtin_amdgcn_mfma_f32_16x16x32_bf16(af[m], bfr[n], acc[m][n], 0, 0, 0);
        __syncthreads();
    }

    const int rowb = blockIdx.x * 128 + (wr << 6) + ((lane >> 4) << 2);
    const int colb = blockIdx.y * 128 + (wc << 6) + (lane & 15);
    #pragma unroll
    for (int m = 0; m < 4; m++) {
        #pragma unroll
        for (int n = 0; n < 4; n++) {
            #pragma unroll
            for (int r = 0; r < 4; r++) {
                int row = rowb + m * 16 + r;
                int col = colb + n * 16;
                float v = acc[m][n][r];
                if (RBIAS) v += bias[row];
                if (RESID) v += resid[(long long)bz * sR + (size_t)row * ldc + col];
                if (RELU)  v = fmaxf(v, 0.0f);
                if (OBF16) ((u16*)C)[(long long)bz * sC + (size_t)row * ldc + col] = f2bf(v);
                else       ((float*)C)[(long long)bz * sC + (size_t)row * ldc + col] = v;
            }
        }
    }
}

// ---------------------------------------------------------------------------
// Transpose+cast: src [b][C][N] fp32 -> dst [b][N][C] bf16, for x/ob/od
// ---------------------------------------------------------------------------
__global__ void transpose_cast(const float* __restrict__ x, const float* __restrict__ ob,
                               const float* __restrict__ od, u16* __restrict__ xt)
{
    __shared__ float t[32][33];
    int z = blockIdx.z, which = z >> 4, b = z & 15;
    const float* src = (which == 0) ? x : (which == 1) ? ob : od;
    const float* s = src + (size_t)b * cC * cN;
    u16* dst = xt + (size_t)which * (cB * cN * cC) + (size_t)b * (cN * cC);
    int n0 = blockIdx.x << 5, c0 = blockIdx.y << 5;
    int tx = threadIdx.x, ty = threadIdx.y;
    #pragma unroll
    for (int i = 0; i < 4; i++) { int r = ty + (i << 3); t[r][tx] = s[(size_t)(c0 + r) * cN + n0 + tx]; }
    __syncthreads();
    #pragma unroll
    for (int i = 0; i < 4; i++) { int r = ty + (i << 3); dst[(size_t)(n0 + r) * cC + c0 + tx] = f2bf(t[tx][r]); }
}

// ---------------------------------------------------------------------------
// Weight prep: cast + concat into bf16 buffers
// ---------------------------------------------------------------------------
__global__ void prep_weights(const float* Wt, const float* Wp,
                             const float* Wgx, const float* Wgb, const float* Wgd,
                             const float* Wwd, const float* Wwxb, const float* Wwb, const float* Wwxd,
                             const float* Wwx, const float* Wout,
                             u16* wtp, u16* wgx, u16* wgb, u16* wgd,
                             u16* ww1, u16* ww2, u16* wwx, u16* wout)
{
    int t = blockIdx.x * 256 + threadIdx.x;   // 65536 threads
    wtp[t]  = f2bf(t < 32768 ? Wt[t] : Wp[t - 32768]);
    wout[t] = f2bf(Wout[t]);
    {
        int o = t >> 8, c = t & 255;
        ww1[t] = f2bf(c < 128 ? Wwd[(o << 7) + c] : Wwxb[(o << 7) + c - 128]);
        ww2[t] = f2bf(c < 128 ? Wwb[(o << 7) + c] : Wwxd[(o << 7) + c - 128]);
    }
    if (t < 32768) {
        wgx[t] = f2bf(Wgx[t]); wgb[t] = f2bf(Wgb[t]); wgd[t] = f2bf(Wgd[t]);
        wwx[t] = f2bf(Wwx[t]);
    }
}

// ---------------------------------------------------------------------------
// Degree computation on S [b][1024][1024] fp32
// ---------------------------------------------------------------------------
__global__ void row_sum(const float* __restrict__ S, float* __restrict__ rs)
{
    int b = blockIdx.y;
    int row = (blockIdx.x << 2) + (threadIdx.x >> 6);
    int lane = threadIdx.x & 63;
    const float* p = S + ((size_t)b << 20) + ((size_t)row << 10);
    float a = 0;
    #pragma unroll
    for (int j = 0; j < 16; j++) a += p[lane + (j << 6)];
    for (int off = 32; off; off >>= 1) a += __shfl_down(a, off, 64);
    if (lane == 0) rs[(b << 10) + row] = a;
}

__global__ void col_sum(const float* __restrict__ S, float* __restrict__ cs)
{
    int b = blockIdx.z, ch = blockIdx.y;
    int col = blockIdx.x * 256 + threadIdx.x;
    const float* p = S + ((size_t)b << 20) + ((size_t)ch << 17) + col;
    float a = 0;
    #pragma unroll 4
    for (int m = 0; m < 128; m++) a += p[(size_t)m << 10];
    cs[(((b << 3) + ch) << 10) + col] = a;
}

__global__ void make_dinv(const float* __restrict__ rs, const float* __restrict__ cs,
                          float* __restrict__ dinv)
{
    int i = blockIdx.x * 256 + threadIdx.x;   // 16384
    int b = i >> 10, n = i & 1023;
    float c = 0;
    #pragma unroll
    for (int j = 0; j < 8; j++) c += cs[(((b << 3) + j) << 10) + n];
    float d = 0.5f * (rs[i] + c);
    dinv[i] = (d != 0.0f) ? rsqrtf(d) : 0.0f;
}

// f[n][m] = 0.5*(S[n][m]+S[m][n]) * dinv[n]*dinv[m]  -> bf16
__global__ void make_f(const float* __restrict__ S, const float* __restrict__ dinv,
                       u16* __restrict__ F)
{
    __shared__ float t[32][33];
    int b = blockIdx.z;
    const float* Sb = S + ((size_t)b << 20);
    int n0 = blockIdx.x << 5, m0 = blockIdx.y << 5;
    int tx = threadIdx.x, ty = threadIdx.y;
    #pragma unroll
    for (int i = 0; i < 4; i++) { int r = ty + (i << 3); t[r][tx] = Sb[((size_t)(m0 + r) << 10) + n0 + tx]; }
    __syncthreads();
    const float* dv = dinv + (b << 10);
    u16* Fb = F + ((size_t)b << 20);
    #pragma unroll
    for (int i = 0; i < 4; i++) {
        int r = ty + (i << 3);
        int n = n0 + r, m = m0 + tx;
        float v = 0.5f * (Sb[((size_t)n << 10) + m] + t[tx][r]) * dv[n] * dv[m];
        Fb[((size_t)n << 10) + m] = f2bf(v);
    }
}

// ---------------------------------------------------------------------------
// BN stats + finalize + combine
// ---------------------------------------------------------------------------
__global__ void bn_stats(const float* __restrict__ s1, const float* __restrict__ s2,
                         float* __restrict__ acc)
{
    int c = threadIdx.x;
    const float* s = blockIdx.y ? s2 : s1;
    float* a = acc + blockIdx.y * 512;
    size_t r0 = (size_t)blockIdx.x * 64;
    float sum = 0, sq = 0;
    for (int r = 0; r < 64; r++) { float v = s[(r0 + r) * 256 + c]; sum += v; sq += v * v; }
    atomicAdd(&a[c], sum);
    atomicAdd(&a[256 + c], sq);
}

__global__ void bn_finalize(const float* __restrict__ acc,
                            const float* g1, const float* b1,
                            const float* g2, const float* b2,
                            float* __restrict__ p)
{
    int c = threadIdx.x;
    const float inv = 1.0f / 16384.0f;
    for (int k = 0; k < 2; k++) {
        float mean = acc[k * 512 + c] * inv;
        float var  = acc[k * 512 + 256 + c] * inv - mean * mean;
        const float* g = k ? g2 : g1;
        const float* be = k ? b2 : b1;
        float sc = g[c] * rsqrtf(var + 1e-5f);
        p[k * 512 + c] = sc;
        p[k * 512 + 256 + c] = be[c] - mean * sc;
    }
}

// pre = bn1(s1) + bn2(s2) + xs + bwx  -> bf16  (layout [b][n][c])
__global__ void combine_kernel(const float* __restrict__ s1, const float* __restrict__ s2,
                               const float* __restrict__ xs, const float* __restrict__ p,
                               const float* __restrict__ bwx, u16* __restrict__ pre)
{
    size_t i = (size_t)blockIdx.x * 256 + threadIdx.x;
    int c = (int)(i & 255);
    float v = p[c] * s1[i] + p[256 + c] + p[512 + c] * s2[i] + p[768 + c] + xs[i] + bwx[c];
    pre[i] = f2bf(v);
}

// ---------------------------------------------------------------------------
extern "C" void kernel_launch(void* const* d_in, const int* in_sizes, int n_in,
                              void* d_out, int out_size, void* d_ws, size_t ws_size,
                              hipStream_t stream)
{
    const float* x    = (const float*)d_in[0];
    const float* ob   = (const float*)d_in[1];
    const float* od   = (const float*)d_in[2];
    const float* Wt   = (const float*)d_in[3];
    const float* Wp   = (const float*)d_in[4];
    const float* Wgx  = (const float*)d_in[5];
    const float* bgx  = (const float*)d_in[6];
    const float* Wgb  = (const float*)d_in[7];
    const float* bgb  = (const float*)d_in[8];
    const float* Wgd  = (const float*)d_in[9];
    const float* bgd  = (const float*)d_in[10];
    const float* Wwx  = (const float*)d_in[11];
    const float* bwx  = (const float*)d_in[12];
    const float* Wwb  = (const float*)d_in[13];
    const float* Wwd  = (const float*)d_in[15];
    const float* Wwxb = (const float*)d_in[17];
    const float* Wwxd = (const float*)d_in[19];
    const float* g1   = (const float*)d_in[21];
    const float* be1  = (const float*)d_in[22];
    const float* g2   = (const float*)d_in[23];
    const float* be2  = (const float*)d_in[24];
    const float* Wout = (const float*)d_in[25];
    const float* bout = (const float*)d_in[26];
    float* out = (float*)d_out;

    char* w = (char*)d_ws;
    u16*   XT   = (u16*)(w);                      // 3 x 8388608 B   [b][n][c] bf16
    u16*   GT   = (u16*)(w + 25165824);           // 3 x 4194304 B   [b][ic][n] bf16
    u16*   TP   = (u16*)(w + 37748736);           // 8388608 B       [b][n][256] bf16 (t|p), reused as PRE
    float* S    = (float*)(w + 46137344);         // 67108864 B      att fp32; later s1/s2/xs
    u16*   F    = (u16*)(w + 113246208);          // 33554432 B      f bf16
    u16*   HS1  = (u16*)(w + 146800640);          // 8388608 B       [b][n][h_dd|h_bx]
    u16*   HS2  = (u16*)(w + 155189248);          // 8388608 B       [b][n][h_bb|h_dx]
    u16*   HXS  = (u16*)(w + 163577856);          // 4194304 B       [b][n][h_xx]
    u16*   WTP  = (u16*)(w + 167772160);          // 131072 B
    u16*   WG   = (u16*)(w + 167903232);          // 3 x 65536 B
    u16*   WW1  = (u16*)(w + 168099840);          // 131072 B
    u16*   WW2  = (u16*)(w + 168230912);          // 131072 B
    u16*   WWX  = (u16*)(w + 168361984);          // 65536 B
    u16*   WOUT = (u16*)(w + 168427520);          // 131072 B
    float* RS   = (float*)(w + 168558592);        // 65536 B
    float* CS   = (float*)(w + 168624128);        // 524288 B
    float* DINV = (float*)(w + 169148416);        // 65536 B
    float* BNA  = (float*)(w + 169213952);        // 4096 B
    float* BNP  = (float*)(w + 169218048);        // 4096 B

    float* S1 = S;
    float* S2 = S + 4194304;
    float* XS = S + 8388608;
    u16*   PRE = TP;

    hipMemsetAsync(BNA, 0, 4096, stream);
    prep_weights<<<dim3(256), dim3(256), 0, stream>>>(Wt, Wp, Wgx, Wgb, Wgd,
        Wwd, Wwxb, Wwb, Wwxd, Wwx, Wout,
        WTP, WG, WG + 32768, WG + 65536, WW1, WW2, WWX, WOUT);
    transpose_cast<<<dim3(32, 8, 48), dim3(32, 8), 0, stream>>>(x, ob, od, XT);

    // g convs:  GT_y[ic][n] = sum_c Wg[ic,c]*X[c,n] + bg[ic]   (bf16 out)
    for (int yi = 0; yi < 3; yi++) {
        const float* bg = (yi == 0) ? bgx : (yi == 1) ? bgb : bgd;
        gemm_bt<false, true, true, false><<<dim3(1, 8, 16), 256, 0, stream>>>(
            WG + yi * 32768, 0, 256,
            XT + (size_t)yi * 4194304, 262144, 256,
            GT + (size_t)yi * 2097152, 131072, 1024,
            256, bg, nullptr, 0);
    }

    for (int yi = 0; yi < 3; yi++) {
        // t|p = relu(X @ [Wt|Wp]^T):  [b][n][256] bf16
        gemm_bt<true, true, false, false><<<dim3(8, 2, 16), 256, 0, stream>>>(
            XT + (size_t)yi * 4194304, 262144, 256,
            WTP, 0, 256,
            TP, 262144, 256,
            256, nullptr, nullptr, 0);
        // S[n][m] = sum_c t[n][c]*p[m][c]   fp32
        gemm_bt<false, false, false, false><<<dim3(8, 8, 16), 256, 0, stream>>>(
            TP, 262144, 256,
            TP + 128, 262144, 256,
            S, 1048576, 1024,
            128, nullptr, nullptr, 0);
        row_sum<<<dim3(256, 16), 256, 0, stream>>>(S, RS);
        col_sum<<<dim3(4, 8, 16), 256, 0, stream>>>(S, CS);
        make_dinv<<<dim3(64), 256, 0, stream>>>(RS, CS, DINV);
        make_f<<<dim3(32, 32, 16), dim3(32, 8), 0, stream>>>(S, DINV, F);
        // aggs: h[n][i] = sum_m f[n][m] * gT[i][m]   bf16
        if (yi == 0) {
            gemm_bt<false, true, false, false><<<dim3(8, 1, 16), 256, 0, stream>>>(
                F, 1048576, 1024, GT, 131072, 1024, HXS, 131072, 128, 1024, nullptr, nullptr, 0);
        } else if (yi == 1) {
            gemm_bt<false, true, false, false><<<dim3(8, 1, 16), 256, 0, stream>>>(
                F, 1048576, 1024, GT + 2097152, 131072, 1024, HS2, 262144, 256, 1024, nullptr, nullptr, 0);
            gemm_bt<false, true, false, false><<<dim3(8, 1, 16), 256, 0, stream>>>(
                F, 1048576, 1024, GT, 131072, 1024, HS1 + 128, 262144, 256, 1024, nullptr, nullptr, 0);
        } else {
            gemm_bt<false, true, false, false><<<dim3(8, 1, 16), 256, 0, stream>>>(
                F, 1048576, 1024, GT + 2 * 2097152, 131072, 1024, HS1, 262144, 256, 1024, nullptr, nullptr, 0);
            gemm_bt<false, true, false, false><<<dim3(8, 1, 16), 256, 0, stream>>>(
                F, 1048576, 1024, GT, 131072, 1024, HS2 + 128, 262144, 256, 1024, nullptr, nullptr, 0);
        }
    }

    // s1 = od_self + x_ob_cross (biases cancel in BN); s2 = ob_self + x_od_cross; xs = Wwx@h_xx
    gemm_bt<false, false, false, false><<<dim3(8, 2, 16), 256, 0, stream>>>(
        HS1, 262144, 256, WW1, 0, 256, S1, 262144, 256, 256, nullptr, nullptr, 0);
    gemm_bt<false, false, false, false><<<dim3(8, 2, 16), 256, 0, stream>>>(
        HS2, 262144, 256, WW2, 0, 256, S2, 262144, 256, 256, nullptr, nullptr, 0);
    gemm_bt<false, false, false, false><<<dim3(8, 2, 16), 256, 0, stream>>>(
        HXS, 131072, 128, WWX, 0, 128, XS, 262144, 256, 128, nullptr, nullptr, 0);

    bn_stats<<<dim3(256, 2), 256, 0, stream>>>(S1, S2, BNA);
    bn_finalize<<<1, 256, 0, stream>>>(BNA, g1, be1, g2, be2, BNP);
    combine_kernel<<<dim3(16384), 256, 0, stream>>>(S1, S2, XS, BNP, bwx, PRE);

    // out[o][n] = sum_c Wout[o,c]*pre[n][c] + bout[o] + x[o][n]
    gemm_bt<false, false, true, true><<<dim3(2, 8, 16), 256, 0, stream>>>(
        WOUT, 0, 256, PRE, 262144, 256, out, 262144, 1024, 256, bout, x, 262144);
}

// Round 2
// 243.540 us; speedup vs baseline: 1.9354x; 1.9354x over previous
//
#include <hip/hip_runtime.h>

#define GAS __attribute__((address_space(1)))
#define LAS __attribute__((address_space(3)))

typedef __attribute__((ext_vector_type(8))) short short8;
typedef __attribute__((ext_vector_type(4))) float f32x4;
typedef unsigned short u16;

constexpr int cB = 16, cC = 256, cIC = 128, cN = 1024;

__device__ __forceinline__ u16 f2bf(float v) {
    unsigned u = __builtin_bit_cast(unsigned, v);
    return (u16)((u + 0x7fffu + ((u >> 16) & 1u)) >> 16);
}
__device__ __forceinline__ float bf2f(u16 v) {
    unsigned u = ((unsigned)v) << 16;
    return __builtin_bit_cast(float, u);
}

// ---------------------------------------------------------------------------
// Shared GEMM core: C[m,n] = sum_k A[m,k]*B[n,k], 128x128 tile, BK=32,
// 4 waves (2x2), mfma_f32_16x16x32_bf16, global_load_lds staging.
// SYMB: B k-index XOR 128 (for the symmetrized attention GEMM).
// ---------------------------------------------------------------------------
template<bool SYMB>
__device__ __forceinline__ void gemm_core(
    const u16* __restrict__ Ab, int lda,
    const u16* __restrict__ Bb, int ldb, int K,
    u16* lsA, u16* lsB, f32x4 (&acc)[4][4])
{
    const int tid  = threadIdx.x;
    const int lane = tid & 63;
    const int wave = tid >> 6;
    const int wr = wave >> 1, wc = wave & 1;
    const int sr = tid >> 2;
    const int sk = (tid & 3) * 8;

    for (int kk = 0; kk < K; kk += 32) {
        const u16* Ak = Ab + kk;
        const u16* Bk = Bb + (SYMB ? (kk ^ 128) : kk);
        __builtin_amdgcn_global_load_lds((GAS void*)(Ak + (size_t)sr * lda + sk),
                                         (LAS void*)(&lsA[wave << 9]), 16, 0, 0);
        __builtin_amdgcn_global_load_lds((GAS void*)(Ak + (size_t)(sr + 64) * lda + sk),
                                         (LAS void*)(&lsA[2048 + (wave << 9)]), 16, 0, 0);
        __builtin_amdgcn_global_load_lds((GAS void*)(Bk + (size_t)sr * ldb + sk),
                                         (LAS void*)(&lsB[wave << 9]), 16, 0, 0);
        __builtin_amdgcn_global_load_lds((GAS void*)(Bk + (size_t)(sr + 64) * ldb + sk),
                                         (LAS void*)(&lsB[2048 + (wave << 9)]), 16, 0, 0);
        __syncthreads();

        short8 af[4], bfr[4];
        #pragma unroll
        for (int m = 0; m < 4; m++)
            af[m] = *(const short8*)&lsA[(((wr << 6) + (m << 4) + (lane & 15)) << 5) + ((lane >> 4) << 3)];
        #pragma unroll
        for (int n = 0; n < 4; n++)
            bfr[n] = *(const short8*)&lsB[(((wc << 6) + (n << 4) + (lane & 15)) << 5) + ((lane >> 4) << 3)];
        #pragma unroll
        for (int m = 0; m < 4; m++)
            #pragma unroll
            for (int n = 0; n < 4; n++)
                acc[m][n] = __builtin_amdgcn_mfma_f32_16x16x32_bf16(af[m], bfr[n], acc[m][n], 0, 0, 0);
        __syncthreads();
    }
}

// ---------------------------------------------------------------------------
// Generic GEMM. Batch-z decomposed as zlo=z&15 (stride s*), zhi=z>>4 (stride s*2).
// RSUM: atomically accumulate fp32 row sums of the written values.
// ---------------------------------------------------------------------------
template<bool RELU, bool OBF16, bool RBIAS, bool RESID, bool SYMB, bool RSUM>
__global__ __launch_bounds__(256) void gemm_bt(
    const u16* __restrict__ A, long long sA, long long sA2, int lda,
    const u16* __restrict__ B, long long sB, long long sB2, int ldb,
    void* __restrict__ C, long long sC, long long sC2, int ldc,
    int K, float alpha,
    const float* __restrict__ bias, int sb2,
    const float* __restrict__ resid, long long sR,
    float* __restrict__ rsum)
{
    __shared__ alignas(16) u16 lsA[128 * 32];
    __shared__ alignas(16) u16 lsB[128 * 32];

    const int lane = threadIdx.x & 63;
    const int wave = threadIdx.x >> 6;
    const int wr = wave >> 1, wc = wave & 1;
    const int zlo = blockIdx.z & 15, zhi = blockIdx.z >> 4;

    const u16* Ab = A + zlo * sA + zhi * sA2 + (size_t)(blockIdx.x * 128) * lda;
    const u16* Bb = B + zlo * sB + zhi * sB2 + (size_t)(blockIdx.y * 128) * ldb;

    f32x4 acc[4][4] = {};
    gemm_core<SYMB>(Ab, lda, Bb, ldb, K, lsA, lsB, acc);

    const int rowb = blockIdx.x * 128 + (wr << 6) + ((lane >> 4) << 2);
    const int colb = blockIdx.y * 128 + (wc << 6) + (lane & 15);
    const long long cbase = zlo * sC + zhi * sC2;
    float rp[4][4] = {};
    #pragma unroll
    for (int m = 0; m < 4; m++) {
        #pragma unroll
        for (int n = 0; n < 4; n++) {
            #pragma unroll
            for (int r = 0; r < 4; r++) {
                int row = rowb + m * 16 + r;
                int col = colb + n * 16;
                float v = acc[m][n][r] * alpha;
                if (RBIAS) v += bias[zhi * sb2 + row];
                if (RESID) v += resid[zlo * sR + (size_t)row * ldc + col];
                if (RELU)  v = fmaxf(v, 0.0f);
                if (RSUM)  rp[m][r] += v;
                if (OBF16) ((u16*)C)[cbase + (size_t)row * ldc + col] = f2bf(v);
                else       ((float*)C)[cbase + (size_t)row * ldc + col] = v;
            }
        }
    }
    if (RSUM) {
        #pragma unroll
        for (int m = 0; m < 4; m++) {
            #pragma unroll
            for (int r = 0; r < 4; r++) {
                float v = rp[m][r];
                v += __shfl_xor(v, 1, 64);
                v += __shfl_xor(v, 2, 64);
                v += __shfl_xor(v, 4, 64);
                v += __shfl_xor(v, 8, 64);
                if ((lane & 15) == 0)
                    atomicAdd(&rsum[((size_t)blockIdx.z << 10) + rowb + m * 16 + r], v);
            }
        }
    }
}

// ---------------------------------------------------------------------------
// Merged aggregation GEMM: h = S_bf16 @ G'^T, epilogue *dinv[row], split C.
// z = which*16 + b; which 0: f_x (N=128), 1: f_b, 2: f_d.
// ---------------------------------------------------------------------------
struct AggArgs {
    const u16* S;            // [3][16][1024][1024] bf16
    const float* dinv;       // [3][16][1024]
    const u16* G[3];         // scaled g, [16][rows][1024]
    u16* C0[3];              // blockIdx.y==0 target
    u16* C1[3];              // blockIdx.y==1 target (nullptr -> skip)
    long long sB[3];
    long long sC[3];
    int ldc[3];
};

__global__ __launch_bounds__(256) void agg_gemm(AggArgs a)
{
    __shared__ alignas(16) u16 lsA[128 * 32];
    __shared__ alignas(16) u16 lsB[128 * 32];

    const int z = blockIdx.z;
    const int which = z >> 4, b = z & 15;
    u16* Cp = blockIdx.y ? a.C1[which] : a.C0[which];
    if (!Cp) return;

    const u16* Ab = a.S + ((size_t)z << 20) + (size_t)(blockIdx.x * 128) * 1024;
    const u16* Bb = a.G[which] + (size_t)b * a.sB[which] + (size_t)(blockIdx.y * 128) * 1024;

    f32x4 acc[4][4] = {};
    gemm_core<false>(Ab, 1024, Bb, 1024, 1024, lsA, lsB, acc);

    const int lane = threadIdx.x & 63;
    const int wave = threadIdx.x >> 6;
    const int wr = wave >> 1, wc = wave & 1;
    const int rowb = blockIdx.x * 128 + (wr << 6) + ((lane >> 4) << 2);
    const int colb = blockIdx.y * 128 + (wc << 6) + (lane & 15);
    const int ldc = a.ldc[which];
    const float* dv = a.dinv + ((size_t)z << 10);
    u16* Cb = Cp + (size_t)b * a.sC[which];
    #pragma unroll
    for (int m = 0; m < 4; m++)
        #pragma unroll
        for (int n = 0; n < 4; n++)
            #pragma unroll
            for (int r = 0; r < 4; r++) {
                int row = rowb + m * 16 + r;
                int col = colb + n * 16;
                Cb[(size_t)row * ldc + col] = f2bf(acc[m][n][r] * dv[row]);
            }
}

// ---------------------------------------------------------------------------
// Transpose+cast: src [b][C][N] fp32 -> dst [yi][b][N][C] bf16
// ---------------------------------------------------------------------------
__global__ void transpose_cast(const float* __restrict__ x, const float* __restrict__ ob,
                               const float* __restrict__ od, u16* __restrict__ xt)
{
    __shared__ float t[32][33];
    int z = blockIdx.z, which = z >> 4, b = z & 15;
    const float* src = (which == 0) ? x : (which == 1) ? ob : od;
    const float* s = src + (size_t)b * cC * cN;
    u16* dst = xt + (size_t)which * (cB * cN * cC) + (size_t)b * (cN * cC);
    int n0 = blockIdx.x << 5, c0 = blockIdx.y << 5;
    int tx = threadIdx.x, ty = threadIdx.y;
    #pragma unroll
    for (int i = 0; i < 4; i++) { int r = ty + (i << 3); t[r][tx] = s[(size_t)(c0 + r) * cN + n0 + tx]; }
    __syncthreads();
    #pragma unroll
    for (int i = 0; i < 4; i++) { int r = ty + (i << 3); dst[(size_t)(n0 + r) * cC + c0 + tx] = f2bf(t[tx][r]); }
}

// ---------------------------------------------------------------------------
// Weight prep: cast + concat
// ---------------------------------------------------------------------------
__global__ void prep_weights(const float* Wt, const float* Wp,
                             const float* Wgx, const float* Wgb, const float* Wgd,
                             const float* bgx, const float* bgb, const float* bgd,
                             const float* Wwd, const float* Wwxb, const float* Wwb, const float* Wwxd,
                             const float* Wwx, const float* Wout,
                             u16* wtp, u16* wg, u16* ww1, u16* ww2, u16* wwx, u16* wout,
                             float* bg)
{
    int t = blockIdx.x * 256 + threadIdx.x;   // 65536 threads
    wtp[t]  = f2bf(t < 32768 ? Wt[t] : Wp[t - 32768]);
    wout[t] = f2bf(Wout[t]);
    {
        int o = t >> 8, c = t & 255;
        ww1[t] = f2bf(c < 128 ? Wwd[(o << 7) + c] : Wwxb[(o << 7) + c - 128]);
        ww2[t] = f2bf(c < 128 ? Wwb[(o << 7) + c] : Wwxd[(o << 7) + c - 128]);
    }
    if (t < 32768) {
        wg[t] = f2bf(Wgx[t]); wg[32768 + t] = f2bf(Wgb[t]); wg[65536 + t] = f2bf(Wgd[t]);
        wwx[t] = f2bf(Wwx[t]);
    }
    if (t < 384) bg[t] = (t < 128) ? bgx[t] : (t < 256) ? bgb[t - 128] : bgd[t - 256];
}

// ---------------------------------------------------------------------------
// dinv[i] = d!=0 ? rsqrt(d) : 0   over [3][16][1024]
// ---------------------------------------------------------------------------
__global__ void make_dinv(const float* __restrict__ rs, float* __restrict__ dinv)
{
    int i = blockIdx.x * 256 + threadIdx.x;   // 49152
    float d = rs[i];
    dinv[i] = (d != 0.0f) ? rsqrtf(d) : 0.0f;
}

// ---------------------------------------------------------------------------
// Build dinv-scaled g buffers (5 slices via blockIdx.y)
// ---------------------------------------------------------------------------
__global__ void scale_g(u16* __restrict__ GXp, u16* __restrict__ GBp, u16* __restrict__ GDp,
                        const u16* __restrict__ GT, const float* __restrict__ DINV)
{
    int y = blockIdx.y;
    const u16* src; u16* dst; const float* dv; int dstRows; int rowOff;
    if (y == 0)      { src = GT;           dst = GXp; dv = DINV;         dstRows = 128; rowOff = 0; }
    else if (y == 1) { src = GT + 2097152; dst = GBp; dv = DINV + 16384; dstRows = 256; rowOff = 0; }
    else if (y == 2) { src = GT;           dst = GBp; dv = DINV + 16384; dstRows = 256; rowOff = 128; }
    else if (y == 3) { src = GT + 4194304; dst = GDp; dv = DINV + 32768; dstRows = 256; rowOff = 0; }
    else             { src = GT;           dst = GDp; dv = DINV + 32768; dstRows = 256; rowOff = 128; }

    int t = blockIdx.x * 256 + threadIdx.x;   // 262144
    int b = t >> 14, rem = t & 16383;
    int row = rem >> 7, mb = (rem & 127) << 3;
    short8 v = *(const short8*)(src + (size_t)b * 131072 + (size_t)row * 1024 + mb);
    const float* d = dv + (b << 10) + mb;
    short8 o;
    #pragma unroll
    for (int j = 0; j < 8; j++) o[j] = (short)f2bf(bf2f((u16)v[j]) * d[j]);
    *(short8*)(dst + (size_t)b * dstRows * 1024 + (size_t)(rowOff + row) * 1024 + mb) = o;
}

// ---------------------------------------------------------------------------
// BN stats (bf16 inputs) + finalize + combine
// ---------------------------------------------------------------------------
__global__ void bn_stats(const u16* __restrict__ s1, const u16* __restrict__ s2,
                         float* __restrict__ acc)
{
    int c = threadIdx.x;
    const u16* s = blockIdx.y ? s2 : s1;
    float* a = acc + blockIdx.y * 512;
    size_t r0 = (size_t)blockIdx.x * 64;
    float sum = 0, sq = 0;
    for (int r = 0; r < 64; r++) { float v = bf2f(s[(r0 + r) * 256 + c]); sum += v; sq += v * v; }
    atomicAdd(&a[c], sum);
    atomicAdd(&a[256 + c], sq);
}

__global__ void bn_finalize(const float* __restrict__ acc,
                            const float* g1, const float* b1,
                            const float* g2, const float* b2,
                            float* __restrict__ p)
{
    int c = threadIdx.x;
    const float inv = 1.0f / 16384.0f;
    for (int k = 0; k < 2; k++) {
        float mean = acc[k * 512 + c] * inv;
        float var  = acc[k * 512 + 256 + c] * inv - mean * mean;
        const float* g = k ? g2 : g1;
        const float* be = k ? b2 : b1;
        float sc = g[c] * rsqrtf(var + 1e-5f);
        p[k * 512 + c] = sc;
        p[k * 512 + 256 + c] = be[c] - mean * sc;
    }
}

__global__ void combine_kernel(const u16* __restrict__ s1, const u16* __restrict__ s2,
                               const u16* __restrict__ xs, const float* __restrict__ p,
                               const float* __restrict__ bwx, u16* __restrict__ pre)
{
    size_t t = (size_t)blockIdx.x * 256 + threadIdx.x;   // 524288
    size_t base = t << 3;
    int c0 = (int)(base & 255);
    short8 a = *(const short8*)(s1 + base);
    short8 b = *(const short8*)(s2 + base);
    short8 cx = *(const short8*)(xs + base);
    short8 o;
    #pragma unroll
    for (int j = 0; j < 8; j++) {
        int c = c0 + j;
        float v = p[c] * bf2f((u16)a[j]) + p[256 + c]
                + p[512 + c] * bf2f((u16)b[j]) + p[768 + c]
                + bf2f((u16)cx[j]) + bwx[c];
        o[j] = (short)f2bf(v);
    }
    *(short8*)(pre + base) = o;
}

// ---------------------------------------------------------------------------
extern "C" void kernel_launch(void* const* d_in, const int* in_sizes, int n_in,
                              void* d_out, int out_size, void* d_ws, size_t ws_size,
                              hipStream_t stream)
{
    const float* x    = (const float*)d_in[0];
    const float* ob   = (const float*)d_in[1];
    const float* od   = (const float*)d_in[2];
    const float* Wt   = (const float*)d_in[3];
    const float* Wp   = (const float*)d_in[4];
    const float* Wgx  = (const float*)d_in[5];
    const float* bgx  = (const float*)d_in[6];
    const float* Wgb  = (const float*)d_in[7];
    const float* bgb  = (const float*)d_in[8];
    const float* Wgd  = (const float*)d_in[9];
    const float* bgd  = (const float*)d_in[10];
    const float* Wwx  = (const float*)d_in[11];
    const float* bwx  = (const float*)d_in[12];
    const float* Wwb  = (const float*)d_in[13];
    const float* Wwd  = (const float*)d_in[15];
    const float* Wwxb = (const float*)d_in[17];
    const float* Wwxd = (const float*)d_in[19];
    const float* g1   = (const float*)d_in[21];
    const float* be1  = (const float*)d_in[22];
    const float* g2   = (const float*)d_in[23];
    const float* be2  = (const float*)d_in[24];
    const float* Wout = (const float*)d_in[25];
    const float* bout = (const float*)d_in[26];
    float* out = (float*)d_out;

    char* w = (char*)d_ws;
    u16*   XT   = (u16*)(w);                    // [3][16][1024][256]  25165824 B
    u16*   TP   = (u16*)(w + 25165824);         // [3][16][1024][256]  25165824 B (reused as PRE)
    u16*   GT   = (u16*)(w + 50331648);         // [3][16][128][1024]  12582912 B
    u16*   S    = (u16*)(w + 62914560);         // [3][16][1024][1024] 100663296 B (reused as S1b/S2b/XSb)
    u16*   GXp  = (u16*)(w + 163577856);        // [16][128][1024]     4194304 B
    u16*   GBp  = (u16*)(w + 167772160);        // [16][256][1024]     8388608 B
    u16*   GDp  = (u16*)(w + 176160768);        // [16][256][1024]     8388608 B
    u16*   HX   = (u16*)(w + 184549376);        // [16][1024][128]     4194304 B
    u16*   HS1  = (u16*)(w + 188743680);        // [16][1024][256]     8388608 B
    u16*   HS2  = (u16*)(w + 197132288);        // [16][1024][256]     8388608 B
    u16*   WTP  = (u16*)(w + 205520896);        // 131072 B
    u16*   WG   = (u16*)(w + 205651968);        // 196608 B
    u16*   WW1  = (u16*)(w + 205848576);        // 131072 B
    u16*   WW2  = (u16*)(w + 205979648);        // 131072 B
    u16*   WWX  = (u16*)(w + 206110720);        // 65536 B
    u16*   WOUT = (u16*)(w + 206176256);        // 131072 B
    float* BGf  = (float*)(w + 206307328);      // 1536 B
    float* RS   = (float*)(w + 206308864);      // [3][16][1024] 196608 B
    float* DINV = (float*)(w + 206505472);      // [3][16][1024] 196608 B
    float* BNA  = (float*)(w + 206702080);      // 4096 B
    float* BNP  = (float*)(w + 206706176);      // 4096 B

    u16* S1b = S;                 // [16][1024][256] bf16 (S dead after agg)
    u16* S2b = S + 4194304;
    u16* XSb = S + 8388608;
    u16* PRE = TP;                // TP dead after sym-S gemm

    // zero RS (+DINV,+BNA) — atomically accumulated each launch
    hipMemsetAsync(RS, 0, 397312, stream);

    prep_weights<<<dim3(256), dim3(256), 0, stream>>>(Wt, Wp, Wgx, Wgb, Wgd,
        bgx, bgb, bgd, Wwd, Wwxb, Wwb, Wwxd, Wwx, Wout,
        WTP, WG, WW1, WW2, WWX, WOUT, BGf);
    transpose_cast<<<dim3(32, 8, 48), dim3(32, 8), 0, stream>>>(x, ob, od, XT);

    // t|p = relu(X @ [Wt|Wp]^T)  -> TP [3][16][1024][256]   (batched over yi)
    gemm_bt<true, true, false, false, false, false><<<dim3(8, 2, 48), 256, 0, stream>>>(
        XT, 262144, 4194304, 256,  WTP, 0, 0, 256,  TP, 262144, 4194304, 256,
        256, 1.0f, nullptr, 0, nullptr, 0, nullptr);

    // g = Wg @ X + bg  -> GT [3][16][128][1024]   (batched over yi)
    gemm_bt<false, true, true, false, false, false><<<dim3(1, 8, 48), 256, 0, stream>>>(
        WG, 0, 32768, 256,  XT, 262144, 4194304, 256,  GT, 131072, 2097152, 1024,
        256, 1.0f, BGf, 128, nullptr, 0, nullptr);

    // S_sym = 0.5*(t p^T + p t^T) -> bf16, fused degree row-sums (batched)
    gemm_bt<false, true, false, false, true, true><<<dim3(8, 8, 48), 256, 0, stream>>>(
        TP, 262144, 4194304, 256,  TP, 262144, 4194304, 256,  S, 1048576, 16777216, 1024,
        256, 0.5f, nullptr, 0, nullptr, 0, RS);

    make_dinv<<<dim3(192), 256, 0, stream>>>(RS, DINV);
    scale_g<<<dim3(1024, 5), 256, 0, stream>>>(GXp, GBp, GDp, GT, DINV);

    // merged aggregation: h = S @ G'^T, * dinv[row]
    AggArgs aa;
    aa.S = S; aa.dinv = DINV;
    aa.G[0] = GXp;  aa.G[1] = GBp;  aa.G[2] = GDp;
    aa.C0[0] = HX;  aa.C0[1] = HS2; aa.C0[2] = HS1;   // y=0: self part
    aa.C1[0] = nullptr; aa.C1[1] = HS1; aa.C1[2] = HS2; // y=1: cross part (cols 128..255)
    aa.sB[0] = 131072;  aa.sB[1] = 262144; aa.sB[2] = 262144;
    aa.sC[0] = 131072;  aa.sC[1] = 262144; aa.sC[2] = 262144;
    aa.ldc[0] = 128;    aa.ldc[1] = 256;   aa.ldc[2] = 256;
    agg_gemm<<<dim3(8, 2, 48), 256, 0, stream>>>(aa);

    // s1 = [Wwd|Wwxb] @ HS1^T rows; s2 = [Wwb|Wwxd] @ HS2; xs = Wwx @ HX
    gemm_bt<false, true, false, false, false, false><<<dim3(8, 2, 16), 256, 0, stream>>>(
        HS1, 262144, 0, 256,  WW1, 0, 0, 256,  S1b, 262144, 0, 256,
        256, 1.0f, nullptr, 0, nullptr, 0, nullptr);
    gemm_bt<false, true, false, false, false, false><<<dim3(8, 2, 16), 256, 0, stream>>>(
        HS2, 262144, 0, 256,  WW2, 0, 0, 256,  S2b, 262144, 0, 256,
        256, 1.0f, nullptr, 0, nullptr, 0, nullptr);
    gemm_bt<false, true, false, false, false, false><<<dim3(8, 2, 16), 256, 0, stream>>>(
        HX, 131072, 0, 128,  WWX, 0, 0, 128,  XSb, 262144, 0, 256,
        128, 1.0f, nullptr, 0, nullptr, 0, nullptr);

    bn_stats<<<dim3(256, 2), 256, 0, stream>>>(S1b, S2b, BNA);
    bn_finalize<<<1, 256, 0, stream>>>(BNA, g1, be1, g2, be2, BNP);
    combine_kernel<<<dim3(2048), 256, 0, stream>>>(S1b, S2b, XSb, BNP, bwx, PRE);

    // out = Wout @ pre + bout + x
    gemm_bt<false, false, true, true, false, false><<<dim3(2, 8, 16), 256, 0, stream>>>(
        WOUT, 0, 0, 256,  PRE, 262144, 0, 256,  out, 262144, 0, 1024,
        256, 1.0f, bout, 0, x, 262144, nullptr);
}